// Round 7
// baseline (499.964 us; speedup 1.0000x reference)
//
#include <hip/hip_runtime.h>

constexpr int kB  = 32;
constexpr int kNQ = 256;   // rows n
constexpr int kNT = 512;   // cols m
constexpr float kInf = 1e30f;
constexpr int kQTile = 8;     // queries per cost block
constexpr int kSlots = 56;    // LDS row-cache entries
constexpr int kStride = 544;  // 8 groups x (64 data + 4 pad) floats
constexpr int kArrCap = 768;  // ARR step bound (termination guard)
constexpr int kListCap = 1024;

// ---------------------------------------------------------------------------
// Kernel 1: final_cost [B, NQ, NT]. 512 thr/block, thread == target t.
// Math per output element bit-identical to the proven kernel.
// ---------------------------------------------------------------------------
__global__ __launch_bounds__(512)
void cost_kernel(const float* __restrict__ trans,
                 const float* __restrict__ qpos,
                 const float* __restrict__ rot,
                 const float* __restrict__ pose,
                 float* __restrict__ cost)
{
    __shared__ float sPose[kNT * 23];   // 47104 B -> 3 blocks/CU

    const int b     = blockIdx.x;
    const int qBase = blockIdx.y * kQTile;
    const int tid   = threadIdx.x;      // target index t

    const float* pb = pose + (size_t)b * kNT * 23;
    for (int idx = tid; idx < kNT * 23; idx += 512) sPose[idx] = pb[idx];
    __syncthreads();

    float T[23];
    #pragma unroll
    for (int d = 0; d < 23; ++d) T[d] = sPose[tid * 23 + d];

    float s = 0.f;
    #pragma unroll
    for (int d = 0; d < 23; ++d) s += fabsf(T[d]);
    const bool valid = (s > 0.f);

    const float* tr = trans + ((size_t)b * kNQ + qBase) * 3;
    const float* qp = qpos  + ((size_t)b * kNQ + qBase) * 16;
    const float* rt = rot   + ((size_t)b * kNQ + qBase) * 4;
    float* cb = cost + ((size_t)b * kNQ + qBase) * kNT + tid;

    #pragma unroll
    for (int q = 0; q < kQTile; ++q) {
        const float Q0 = tr[q * 3 + 0], Q1 = tr[q * 3 + 1], Q2 = tr[q * 3 + 2];
        float a = fabsf(Q0 - T[0]);
        a += fabsf(Q1 - T[1]);
        a += fabsf(Q2 - T[2]);
        float bsum = 0.f;
        #pragma unroll
        for (int d = 0; d < 16; ++d) bsum += fabsf(qp[q * 16 + d] - T[3 + d]);
        const float r0 = rt[q * 4 + 0], r1 = rt[q * 4 + 1];
        const float r2 = rt[q * 4 + 2], r3 = rt[q * 4 + 3];
        float dot = r0 * T[19] + r1 * T[20] + r2 * T[21] + r3 * T[22];
        float c = (a + bsum) + (1.0f - fabsf(dot));
        cb[(size_t)q * kNT] = valid ? c : kInf;
    }
}

// Wave64 min-reduction via DPP (rocPRIM pattern). All inputs are non-negative
// float bit-patterns (incl +inf sentinel), so u32 order == f32 order.
__device__ __forceinline__ unsigned wave_min_u32(unsigned x) {
    unsigned t;
    t = (unsigned)__builtin_amdgcn_update_dpp((int)0xFFFFFFFF, (int)x, 0x111, 0xF, 0xF, false); x = t < x ? t : x; // row_shr:1
    t = (unsigned)__builtin_amdgcn_update_dpp((int)0xFFFFFFFF, (int)x, 0x112, 0xF, 0xF, false); x = t < x ? t : x; // row_shr:2
    t = (unsigned)__builtin_amdgcn_update_dpp((int)0xFFFFFFFF, (int)x, 0x114, 0xF, 0xF, false); x = t < x ? t : x; // row_shr:4
    t = (unsigned)__builtin_amdgcn_update_dpp((int)0xFFFFFFFF, (int)x, 0x118, 0xF, 0xF, false); x = t < x ? t : x; // row_shr:8
    t = (unsigned)__builtin_amdgcn_update_dpp((int)0xFFFFFFFF, (int)x, 0x142, 0xF, 0xF, false); x = t < x ? t : x; // row_bcast:15
    t = (unsigned)__builtin_amdgcn_update_dpp((int)0xFFFFFFFF, (int)x, 0x143, 0xF, 0xF, false); x = t < x ? t : x; // row_bcast:31
    return (unsigned)__builtin_amdgcn_readlane((int)x, 63);
}

// Wave64 (min, 2nd-min) float reduction via the same shr/bcast pattern.
// Lane 63's merge chain only ever combines DISJOINT lane ranges
// ({62},{60..61},{56..59},{48..55} prefixes, then {32..47}, then {0..31}),
// so the 2nd-min at lane 63 is exact. Values finite (no NaN/Inf inputs);
// out-of-range DPP lanes supply +inf (identity).
__device__ __forceinline__ void wave_min2_f32(float &m1, float &m2) {
#define MIN2_STEP(CTRL)                                                          \
    {                                                                            \
        const float o1 = __int_as_float(__builtin_amdgcn_update_dpp(             \
            0x7F800000, __float_as_int(m1), CTRL, 0xF, 0xF, false));             \
        const float o2 = __int_as_float(__builtin_amdgcn_update_dpp(             \
            0x7F800000, __float_as_int(m2), CTRL, 0xF, 0xF, false));             \
        const bool  lt  = o1 < m1;                                               \
        const float n2a = fminf(m2, o1);                                         \
        const float n2b = fminf(o2, m1);                                         \
        m2 = lt ? n2b : n2a;                                                     \
        m1 = lt ? o1 : m1;                                                       \
    }
    MIN2_STEP(0x111) MIN2_STEP(0x112) MIN2_STEP(0x114)
    MIN2_STEP(0x118) MIN2_STEP(0x142) MIN2_STEP(0x143)
#undef MIN2_STEP
}

// ---------------------------------------------------------------------------
// Kernel 2: JV LSAP. SAP sweep loop is EXACT R0 code (proven 356us floor).
// NEW Phase B2: JV augmenting row reduction (ARR) between greedy init and
// SAP. For each free row i: r1@j1 = min_j(C[i][j]-v[j]), r2 = 2nd min;
// u[i]=r2; if r1<r2: v[j1] -= (r2-r1); assign i->j1, displacing the previous
// owner (re-queued). Invariants preserved EXACTLY: v only decreases (others'
// slack grows -> feasibility kept), new matched arc has zero slack, rows not
// processed keep Phase-A duals. Any partial ARR state is a valid SAP start,
// so step/list caps guarantee termination without risking correctness.
// Optimal assignment is unique for this data => output indices unchanged.
// ---------------------------------------------------------------------------
__global__ __launch_bounds__(256)
void hungarian_kernel(const float* __restrict__ cost,
                      float* __restrict__ outInds,
                      float* __restrict__ outMask)
{
    __shared__ float rowCache[kSlots * kStride];  // 121856 B
    __shared__ float u[kNQ];
    __shared__ int   col4row[kNQ];
    __shared__ int   row4col[kNT];
    __shared__ int   colBest[kNT];
    __shared__ int   pathL[kNT];
    __shared__ int   rowArg[kNQ];
    __shared__ int   freeL[kListCap];
    __shared__ int   flCnt;

    const int b   = blockIdx.x;
    const int tid = threadIdx.x;
    const float* __restrict__ C = cost + (size_t)b * kNQ * kNT;

    // ---- Phase A: row minima + greedy matching (thread t == row t) ----
    {
        const float4* Crow = (const float4*)(C + (size_t)tid * kNT);
        float bm = kInf; int barg = 0;
        #pragma unroll 4
        for (int j4 = 0; j4 < kNT / 4; ++j4) {
            float4 cc = Crow[j4];
            const int jb = j4 * 4;
            if (cc.x < bm) { bm = cc.x; barg = jb + 0; }
            if (cc.y < bm) { bm = cc.y; barg = jb + 1; }
            if (cc.z < bm) { bm = cc.z; barg = jb + 2; }
            if (cc.w < bm) { bm = cc.w; barg = jb + 3; }
        }
        u[tid]      = bm;   // feasible: C - u - 0 >= 0 exactly; matched slack == 0 exactly
        rowArg[tid] = barg;
        col4row[tid] = -1;
    }
    row4col[tid] = -1;         row4col[tid + 256] = -1;
    colBest[tid] = 0x7fffffff; colBest[tid + 256] = 0x7fffffff;
    __syncthreads();
    atomicMin(&colBest[rowArg[tid]], tid);
    __syncthreads();
    {
        const int j = rowArg[tid];
        if (colBest[j] == tid) { col4row[tid] = j; row4col[j] = tid; }
    }
    __syncthreads();

    // ---- Phase B2 + C: wave 0 only (wave-synchronous) ----
    if (tid < 64) {
        const int lane = tid;
        const int laneOff = (lane >> 3) * 68 + (lane & 7) * 8;
        typedef float v2f __attribute__((ext_vector_type(2)));

        float vR[8];
        #pragma unroll
        for (int c = 0; c < 8; ++c) vR[c] = 0.f;

        int tagReg = -1;   // lane-indexed cache tag (slot == lane)
        int rr     = 0;    // wave-uniform round-robin fill pointer

        // ---- build free-row list ----
        if (lane == 0) flCnt = 0;
        #pragma unroll
        for (int e = 0; e < 4; ++e) {
            const int r = lane * 4 + e;
            if (col4row[r] < 0) { const int t = atomicAdd(&flCnt, 1); freeL[t] = r; }
        }
        __threadfence_block();

        // ---- Phase B2: augmenting row reduction ----
        {
            int head = 0;
            for (int steps = 0; steps < kArrCap; ++steps) {
                const int tail = flCnt;              // uniform LDS broadcast
                if (head >= tail) break;
                const int i = freeL[head]; ++head;   // uniform
                if (col4row[i] >= 0) continue;       // safety (shouldn't trigger)

                // row load via the proven ballot-associative cache; ARR rows
                // ARE cached (revisited on displacement and in SAP).
                const unsigned long long hm = __ballot(tagReg == i);
                float4 p0, p1;
                if (hm != 0ull) {
                    const int slot = (int)__ffsll(hm) - 1;
                    const float4* lp = (const float4*)&rowCache[slot * kStride + laneOff];
                    p0 = lp[0]; p1 = lp[1];
                } else {
                    const float4* rp = (const float4*)(C + (size_t)i * kNT + lane * 8);
                    p0 = rp[0]; p1 = rp[1];
                    float4* wp = (float4*)&rowCache[rr * kStride + laneOff];
                    wp[0] = p0; wp[1] = p1;
                    if (lane == rr) tagReg = i;
                    rr = rr + 1; if (rr == kSlots) rr = 0;
                }

                // reduced costs vs column prices (float domain; may be <0)
                const float vals[8] = { p0.x, p0.y, p0.z, p0.w,
                                        p1.x, p1.y, p1.z, p1.w };
                float rc8[8];
                #pragma unroll
                for (int c = 0; c < 8; ++c) rc8[c] = vals[c] - vR[c];

                // per-lane (min, 2nd-min, argmin) over 8
                float lm1, lm2; int lc;
                {
                    float a1[4], a2[4]; int ai[4];
                    #pragma unroll
                    for (int p = 0; p < 4; ++p) {
                        const float x = rc8[2 * p], y = rc8[2 * p + 1];
                        const bool sw = y < x;
                        a1[p] = sw ? y : x;
                        a2[p] = sw ? x : y;
                        ai[p] = sw ? 2 * p + 1 : 2 * p;
                    }
                    float b1A, b2A; int biA;
                    { const bool lt = a1[1] < a1[0];
                      b2A = lt ? fminf(a2[1], a1[0]) : fminf(a2[0], a1[1]);
                      b1A = lt ? a1[1] : a1[0];
                      biA = lt ? ai[1] : ai[0]; }
                    float b1B, b2B; int biB;
                    { const bool lt = a1[3] < a1[2];
                      b2B = lt ? fminf(a2[3], a1[2]) : fminf(a2[2], a1[3]);
                      b1B = lt ? a1[3] : a1[2];
                      biB = lt ? ai[3] : ai[2]; }
                    { const bool lt = b1B < b1A;
                      lm2 = lt ? fminf(b2B, b1A) : fminf(b2A, b1B);
                      lm1 = lt ? b1B : b1A;
                      lc  = lt ? biB : biA; }
                }
                const int spec = row4col[lane * 8 + lc];  // owner prefetch (hidden under DPP)

                float w1 = lm1, w2 = lm2;
                wave_min2_f32(w1, w2);
                const float g1 = __int_as_float(__builtin_amdgcn_readlane(__float_as_int(w1), 63));
                const float g2 = __int_as_float(__builtin_amdgcn_readlane(__float_as_int(w2), 63));

                const unsigned long long bal = __ballot(lm1 == g1);
                const int wl  = (int)__ffsll(bal) - 1;
                const int j1  = __builtin_amdgcn_readlane(lane * 8 + lc, wl);
                const int own = __builtin_amdgcn_readlane(spec, wl);

                // dual updates: u[i] = r2; v[j1] -= (r2 - r1)
                if (wl == lane) {
                    const int lcw = j1 & 7;
                    const float d = g2 - g1;
                    #pragma unroll
                    for (int c = 0; c < 8; ++c) if (c == lcw) vR[c] -= d;
                }
                if (lane == 0) {
                    u[i] = g2;
                    row4col[j1] = i;
                    col4row[i]  = j1;
                    if (own >= 0) {
                        col4row[own] = -1;
                        const int t = flCnt;
                        if (t < kListCap) { freeL[t] = own; flCnt = t + 1; }
                    }
                }
                __threadfence_block();
            }
        }

        // ---- Phase C: augmenting searches (EXACT R0 code) ----
        for (int cur = 0; cur < kNQ; ++cur) {
            if (col4row[cur] >= 0) continue;   // uniform branch

            float spcR[8]; int pathR[8]; float mskA[8]; float frzV[8]; int frzP[8];
            #pragma unroll
            for (int c = 0; c < 8; ++c) {
                spcR[c] = kInf; pathR[c] = -1; mskA[c] = 0.f;
                frzV[c] = 0.f;  frzP[c] = -1;
            }
            unsigned scMask = 0;

            int   i      = cur;
            float minVal = 0.f;
            int   sink   = -1;

            for (int guard = 0; guard < kNT + 2 && sink < 0; ++guard) {
                const float ui = u[i];            // LDS read, overlaps row fetch
                float4 p0, p1;
                const unsigned long long hm = __ballot(tagReg == i);
                if (hm != 0ull) {                 // cache hit (wave-uniform)
                    const int slot = (int)__ffsll(hm) - 1;
                    const float4* lp = (const float4*)&rowCache[slot * kStride + laneOff];
                    p0 = lp[0]; p1 = lp[1];
                } else {                          // miss: global (L2) load
                    const float4* rp = (const float4*)(C + (size_t)i * kNT + lane * 8);
                    p0 = rp[0]; p1 = rp[1];
                    if (guard != 0) {             // don't cache one-shot cur rows
                        float4* wp = (float4*)&rowCache[rr * kStride + laneOff];
                        wp[0] = p0; wp[1] = p1;   // fire-and-forget
                        if (lane == rr) tagReg = i;
                        rr = rr + 1; if (rr == kSlots) rr = 0;
                    }
                }

                // ---- UNMASKED packed relax (value-exact op order) ----
                const v2f cc2[4] = { {p0.x, p0.y}, {p0.z, p0.w},
                                     {p1.x, p1.y}, {p1.z, p1.w} };
                const v2f mv2 = { minVal, minVal };
                const v2f ui2 = { ui, ui };
                float r8[8];
                #pragma unroll
                for (int p = 0; p < 4; ++p) {
                    const v2f vv = { vR[2*p], vR[2*p + 1] };
                    const v2f rp2 = ((mv2 + cc2[p]) - ui2) - vv;
                    r8[2*p] = rp2.x; r8[2*p + 1] = rp2.y;
                }
                #pragma unroll
                for (int c = 0; c < 8; ++c) {
                    const bool lt = r8[c] < spcR[c];
                    spcR[c]  = lt ? r8[c] : spcR[c];
                    pathR[c] = lt ? i : pathR[c];
                }

                // ---- masked local argmin: msk = spc + {0|+inf}, u32 tree ----
                float mskv[8];
                #pragma unroll
                for (int p = 0; p < 4; ++p) {
                    const v2f s2 = { spcR[2*p], spcR[2*p + 1] };
                    const v2f a2 = { mskA[2*p], mskA[2*p + 1] };
                    const v2f m2 = s2 + a2;
                    mskv[2*p] = m2.x; mskv[2*p + 1] = m2.y;
                }
                unsigned sp[8];
                #pragma unroll
                for (int c = 0; c < 8; ++c) sp[c] = __float_as_uint(mskv[c]);
                unsigned mA = sp[1] < sp[0] ? sp[1] : sp[0]; int aA = sp[1] < sp[0] ? 1 : 0;
                unsigned mB = sp[3] < sp[2] ? sp[3] : sp[2]; int aB = sp[3] < sp[2] ? 3 : 2;
                unsigned mC = sp[5] < sp[4] ? sp[5] : sp[4]; int aC = sp[5] < sp[4] ? 5 : 4;
                unsigned mD = sp[7] < sp[6] ? sp[7] : sp[6]; int aD = sp[7] < sp[6] ? 7 : 6;
                unsigned mAB = mB < mA ? mB : mA; int aAB = mB < mA ? aB : aA;
                unsigned mCD = mD < mC ? mD : mC; int aCD = mD < mC ? aD : aC;
                unsigned lvu = mCD < mAB ? mCD : mAB; int lc = mCD < mAB ? aCD : aAB;
                const int lix  = lane * 8 + lc;
                const int spec = row4col[lix];          // speculative owner prefetch

                const unsigned gmu = wave_min_u32(lvu); // hides the LDS read above
                const unsigned long long bal = __ballot(lvu == gmu);
                const int wl    = (int)__ffsll(bal) - 1;
                const int jstar = __builtin_amdgcn_readlane(lix, wl);
                const int own   = __builtin_amdgcn_readlane(spec, wl);
                minVal = __uint_as_float(gmu);

                if (own < 0) sink = jstar;
                else         i    = own;

                if (wl == lane) {                 // freeze sweep-time state
                    const int lcw = jstar & 7;
                    scMask |= 1u << lcw;
                    #pragma unroll
                    for (int c = 0; c < 8; ++c) {
                        if (c == lcw) {
                            mskA[c] = __builtin_inff();
                            frzV[c] = minVal;     // == spcR[c] at sweep time
                            frzP[c] = pathR[c];
                        }
                    }
                }
            }

            // ---- dual updates (sweep-time values, per swept column) ----
            if (lane == 0) u[cur] += minVal;
            #pragma unroll
            for (int c = 0; c < 8; ++c) {
                if ((scMask >> c) & 1u) {
                    const int j = lane * 8 + c;
                    const int r = row4col[j];
                    const float d = minVal - frzV[c];
                    if (r >= 0) u[r] += d;   // owners distinct (matching invariant)
                    vR[c] -= d;
                    pathL[j] = frzP[c];
                }
            }
            __threadfence_block();

            // ---- augment along alternating path (lane 0) ----
            if (lane == 0 && sink >= 0) {
                int j = sink;
                while (true) {
                    const int pi = pathL[j];
                    row4col[j] = pi;
                    const int nj = col4row[pi];
                    col4row[pi] = j;
                    if (pi == cur) break;
                    j = nj;
                }
            }
            __threadfence_block();
        }
    }
    __syncthreads();

    outInds[(size_t)b * kNQ + tid] = (float)col4row[tid];
    outMask[(size_t)b * kNQ + tid] = 1.0f;
}

extern "C" void kernel_launch(void* const* d_in, const int* in_sizes, int n_in,
                              void* d_out, int out_size, void* d_ws, size_t ws_size,
                              hipStream_t stream) {
    const float* trans = (const float*)d_in[0];
    const float* qpos  = (const float*)d_in[1];
    const float* rot   = (const float*)d_in[2];
    const float* pose  = (const float*)d_in[3];

    float* out  = (float*)d_out;
    float* cost = out;
    float* inds = out + (size_t)kB * kNQ * kNT;
    float* mask = inds + (size_t)kB * kNQ;

    dim3 g1(kB, kNQ / kQTile);
    cost_kernel<<<g1, 512, 0, stream>>>(trans, qpos, rot, pose, cost);
    hungarian_kernel<<<kB, 256, 0, stream>>>(cost, inds, mask);
}